// Round 3
// baseline (1142.547 us; speedup 1.0000x reference)
//
#include <hip/hip_runtime.h>

static constexpr int kN  = 4096;   // nodes
static constexpr int kE  = 128;    // embed
static constexpr int kH  = 8;      // heads
static constexpr int kD  = 16;     // head dim
static constexpr int kNE = 65536;  // edges

typedef float f4 __attribute__((ext_vector_type(4)));  // native vec for nontemporal store

// ---------------- Kernel 1: type-specific QKV projections (+ counts zeroing) ----------------
// grid kN, block kE(=128). y[n,f] = sum_e x[n,e]*W[t][e,f] + b[t][f]
__global__ void proj_kernel(const float* __restrict__ q_in, const float* __restrict__ k_in,
                            const float* __restrict__ v_in,
                            const float* __restrict__ Wq, const float* __restrict__ bq,
                            const float* __restrict__ Wk, const float* __restrict__ bk,
                            const float* __restrict__ Wv, const float* __restrict__ bv,
                            const int* __restrict__ node_types,
                            float* __restrict__ Q, float* __restrict__ K, float* __restrict__ V,
                            int* __restrict__ counts) {
    const int n = blockIdx.x;
    const int f = threadIdx.x;
    if (f == 0) counts[n] = 0;  // zero CSR counts for the count kernel (fused launch)
    __shared__ float xq[kE], xk[kE], xv[kE];
    xq[f] = q_in[n * kE + f];
    xk[f] = k_in[n * kE + f];
    xv[f] = v_in[n * kE + f];
    __syncthreads();
    const int t = node_types[n];
    const float* wq = Wq + (size_t)t * kE * kE;
    const float* wk = Wk + (size_t)t * kE * kE;
    const float* wv = Wv + (size_t)t * kE * kE;
    float aq = bq[t * kE + f], ak = bk[t * kE + f], av = bv[t * kE + f];
#pragma unroll 8
    for (int e = 0; e < kE; ++e) {
        aq += xq[e] * wq[e * kE + f];
        ak += xk[e] * wk[e * kE + f];
        av += xv[e] * wv[e * kE + f];
    }
    Q[n * kE + f] = aq;
    K[n * kE + f] = ak;
    V[n * kE + f] = av;
}

// ---------------- CSR build (edges grouped by target row) ----------------
__global__ void csr_count_kernel(const int* __restrict__ edge_index, int* __restrict__ counts) {
    const int e = blockIdx.x * 256 + threadIdx.x;
    atomicAdd(&counts[edge_index[kNE + e]], 1);  // tgt
}

// 1 block, 1024 threads, 4 counts each: exclusive prefix -> P (row starts)
__global__ void csr_scan_kernel(const int* __restrict__ counts, int* __restrict__ P) {
    __shared__ int buf[1024];
    const int t = threadIdx.x;
    int c[4];
    int s = 0;
#pragma unroll
    for (int u = 0; u < 4; ++u) { c[u] = counts[t * 4 + u]; s += c[u]; }
    buf[t] = s;
    __syncthreads();
    int v = s;
    for (int off = 1; off < 1024; off <<= 1) {
        const int add = (t >= off) ? buf[t - off] : 0;
        __syncthreads();
        v += add;
        buf[t] = v;
        __syncthreads();
    }
    int run = v - s;  // exclusive prefix
#pragma unroll
    for (int u = 0; u < 4; ++u) { P[t * 4 + u] = run; run += c[u]; }
}

// scatter: after this P[i] == END of row i (start of row i+1). entry = src | et<<12 (fits u16)
__global__ void csr_scatter_kernel(const int* __restrict__ edge_index,
                                   const int* __restrict__ edge_types,
                                   int* __restrict__ P, unsigned short* __restrict__ entries) {
    const int e = blockIdx.x * 256 + threadIdx.x;
    const int src = edge_index[e];
    const int tgt = edge_index[kNE + e];
    const int et  = edge_types[e];
    const int pos = atomicAdd(&P[tgt], 1);
    entries[pos] = (unsigned short)(src | (et << 12));
}

// ---------------- Kernel 2: fused scores + bias + softmax + attn-write + PV ----------------
// grid (kN/4, kH), block 512 (8 waves). LDS ~66 KB -> 2 blocks/CU = 16 waves/CU.
// wave w owns j-range [w*512, w*512+512) for scores/PV; wave-pair (2r,2r+1) owns row r
// for bias/softmax (each wave does half the row). Attn store fused into the PV loop.
__global__ __launch_bounds__(512, 4) void attn_fused_kernel(
        const float* __restrict__ Q, const float* __restrict__ K, const float* __restrict__ V,
        const int* __restrict__ Pend, const unsigned short* __restrict__ entries,
        const float* __restrict__ edge_bias,
        float* __restrict__ attn, float* __restrict__ OT) {
    const int i0 = blockIdx.x * 4;
    const int h  = blockIdx.y;
    const int t  = threadIdx.x;
    const int w  = t >> 6;        // 0..7
    const int lane = t & 63;
    const int jw = w * 512;

    __shared__ float S[4][kN];        // 64 KB
    __shared__ float ebias_s[3 * kH];
    __shared__ float pmax[4][2];
    __shared__ float psum[4][2];
    __shared__ float red[8][64];

    if (t < 3 * kH) ebias_s[t] = edge_bias[t];

    // ---- phase 1: scores. lane owns column j; K loads software-pipelined (depth 1) ----
    {
        float4 qv[4][4];
#pragma unroll
        for (int r = 0; r < 4; ++r) {
            const float4* qp = (const float4*)(Q + (size_t)(i0 + r) * kE + h * kD);
#pragma unroll
            for (int u = 0; u < 4; ++u) qv[r][u] = qp[u];
        }
        const float* kb = K + (size_t)(jw + lane) * kE + h * kD;
        float4 kc[4], kn[4];
        {
            const float4* kp = (const float4*)kb;
#pragma unroll
            for (int u = 0; u < 4; ++u) kc[u] = kp[u];
        }
#pragma unroll
        for (int k = 0; k < 8; ++k) {
            if (k < 7) {
                const float4* kp = (const float4*)(kb + (size_t)(k + 1) * 64 * kE);
#pragma unroll
                for (int u = 0; u < 4; ++u) kn[u] = kp[u];
            }
            const int j = jw + k * 64 + lane;
#pragma unroll
            for (int r = 0; r < 4; ++r) {
                float a = qv[r][0].x * kc[0].x + qv[r][0].y * kc[0].y + qv[r][0].z * kc[0].z + qv[r][0].w * kc[0].w;
                a += qv[r][1].x * kc[1].x + qv[r][1].y * kc[1].y + qv[r][1].z * kc[1].z + qv[r][1].w * kc[1].w;
                a += qv[r][2].x * kc[2].x + qv[r][2].y * kc[2].y + qv[r][2].z * kc[2].z + qv[r][2].w * kc[2].w;
                a += qv[r][3].x * kc[3].x + qv[r][3].y * kc[3].y + qv[r][3].z * kc[3].z + qv[r][3].w * kc[3].w;
                S[r][j] = a * 0.25f;  // 1/sqrt(16)
            }
#pragma unroll
            for (int u = 0; u < 4; ++u) kc[u] = kn[u];
        }
    }
    __syncthreads();

    // ---- phase 2: edge bias into LDS (wave pair (2r,2r+1) splits row r's edge list) ----
    {
        const int r = w >> 1;
        const int i = i0 + r;
        const int beg = (i == 0) ? 0 : Pend[i - 1];
        const int end = Pend[i];
        for (int idx = beg + (w & 1) * 64 + lane; idx < end; idx += 128) {
            const unsigned int en = entries[idx];
            atomicAdd(&S[r][en & 0xFFFu], ebias_s[(en >> 12) * kH + h]);
        }
    }
    __syncthreads();

    // ---- phase 3a: per-half-row max ----
    {
        const int r = w >> 1, hf = w & 1;
        const float4* srow4 = (const float4*)&S[r][0];
        const int base = hf * 512;
        float m = -3.4e38f;
#pragma unroll
        for (int kk = 0; kk < 8; ++kk) {
            const float4 sv = srow4[base + kk * 64 + lane];
            m = fmaxf(m, fmaxf(fmaxf(sv.x, sv.y), fmaxf(sv.z, sv.w)));
        }
#pragma unroll
        for (int off = 32; off > 0; off >>= 1) m = fmaxf(m, __shfl_xor(m, off, 64));
        if (lane == 0) pmax[r][hf] = m;
    }
    __syncthreads();

    // ---- phase 3b: exp (stored back unnormalized) + per-half-row sum ----
    {
        const int r = w >> 1, hf = w & 1;
        float4* srow4 = (float4*)&S[r][0];
        const int base = hf * 512;
        const float m = fmaxf(pmax[r][0], pmax[r][1]);
        float sum = 0.f;
#pragma unroll 2
        for (int kk = 0; kk < 8; ++kk) {
            float4 sv = srow4[base + kk * 64 + lane];
            sv.x = __expf(sv.x - m); sv.y = __expf(sv.y - m);
            sv.z = __expf(sv.z - m); sv.w = __expf(sv.w - m);
            srow4[base + kk * 64 + lane] = sv;
            sum += (sv.x + sv.y) + (sv.z + sv.w);
        }
#pragma unroll
        for (int off = 32; off > 0; off >>= 1) sum += __shfl_xor(sum, off, 64);
        if (lane == 0) psum[r][hf] = sum;
    }
    __syncthreads();

    // ---- phase 4: PV + fused normalized-attn store; V/S loads software-pipelined ----
    {
        float invr[4];
#pragma unroll
        for (int r = 0; r < 4; ++r) invr[r] = 1.f / (psum[r][0] + psum[r][1]);

        float A[64];  // A[r*16+d]
#pragma unroll
        for (int m2 = 0; m2 < 64; ++m2) A[m2] = 0.f;

        const float* vb = V + (size_t)(jw + lane) * kE + h * kD;
        float* abase = attn + ((size_t)h * kN + i0) * kN;  // + r*kN + j
        float4 vc[4], vn[4];
        float sc[4], sn[4];
        {
            const float4* vp = (const float4*)vb;
#pragma unroll
            for (int u = 0; u < 4; ++u) vc[u] = vp[u];
#pragma unroll
            for (int r = 0; r < 4; ++r) sc[r] = S[r][jw + lane];
        }
#pragma unroll
        for (int k = 0; k < 8; ++k) {
            const int j = jw + k * 64 + lane;
            if (k < 7) {
                const float4* vp = (const float4*)(vb + (size_t)(k + 1) * 64 * kE);
#pragma unroll
                for (int u = 0; u < 4; ++u) vn[u] = vp[u];
#pragma unroll
                for (int r = 0; r < 4; ++r) sn[r] = S[r][j + 64];
            }
            // normalized attn store (overlaps with FMAs below)
#pragma unroll
            for (int r = 0; r < 4; ++r)
                __builtin_nontemporal_store(sc[r] * invr[r], abase + (size_t)r * kN + j);
#pragma unroll
            for (int r = 0; r < 4; ++r) {
                const float s = sc[r];
                A[r*16+ 0] += s * vc[0].x; A[r*16+ 1] += s * vc[0].y; A[r*16+ 2] += s * vc[0].z; A[r*16+ 3] += s * vc[0].w;
                A[r*16+ 4] += s * vc[1].x; A[r*16+ 5] += s * vc[1].y; A[r*16+ 6] += s * vc[1].z; A[r*16+ 7] += s * vc[1].w;
                A[r*16+ 8] += s * vc[2].x; A[r*16+ 9] += s * vc[2].y; A[r*16+10] += s * vc[2].z; A[r*16+11] += s * vc[2].w;
                A[r*16+12] += s * vc[3].x; A[r*16+13] += s * vc[3].y; A[r*16+14] += s * vc[3].z; A[r*16+15] += s * vc[3].w;
            }
#pragma unroll
            for (int u = 0; u < 4; ++u) vc[u] = vn[u];
#pragma unroll
            for (int r = 0; r < 4; ++r) sc[r] = sn[r];
        }
        // reduce-and-distribute across lanes: after 6 folds, lane l holds total of A[l]
#define FOLD(OFF, HALF)                                                   \
        {                                                                 \
            const bool hi = (lane & OFF) != 0;                            \
            _Pragma("unroll")                                             \
            for (int i2 = 0; i2 < HALF; ++i2) {                           \
                const float a = A[i2], b = A[i2 + HALF];                  \
                float keep = hi ? b : a;                                  \
                const float send = hi ? a : b;                            \
                keep += __shfl_xor(send, OFF, 64);                        \
                A[i2] = keep;                                             \
            }                                                             \
        }
        FOLD(32, 32) FOLD(16, 16) FOLD(8, 8) FOLD(4, 4) FOLD(2, 2) FOLD(1, 1)
#undef FOLD
        red[w][lane] = A[0];
    }
    __syncthreads();
    if (t < 64) {
        const int r = t >> 4, d = t & 15;
        float acc = 0.f;
#pragma unroll
        for (int u = 0; u < 8; ++u) acc += red[u][t];
        const float inv = 1.f / (psum[r][0] + psum[r][1]);
        OT[(size_t)(i0 + r) * kE + h * kD + d] = acc * inv;
    }
}

// ---------------- Kernel 3: output projection (in-place safe: row staged in LDS) ----------------
__global__ void out_proj_kernel(const float* __restrict__ OT, const float* __restrict__ Wo,
                                const float* __restrict__ bo, float* __restrict__ out) {
    const int n = blockIdx.x, f = threadIdx.x;
    __shared__ float x[kE];
    x[f] = OT[n * kE + f];
    __syncthreads();
    float a = bo[f];
#pragma unroll 8
    for (int e = 0; e < kE; ++e) a += x[e] * Wo[e * kE + f];
    out[n * kE + f] = a;
}

extern "C" void kernel_launch(void* const* d_in, const int* in_sizes, int n_in,
                              void* d_out, int out_size, void* d_ws, size_t ws_size,
                              hipStream_t stream) {
    const float* query = (const float*)d_in[0];
    const float* key_  = (const float*)d_in[1];
    const float* value = (const float*)d_in[2];
    const float* Wq    = (const float*)d_in[3];
    const float* bq    = (const float*)d_in[4];
    const float* Wk    = (const float*)d_in[5];
    const float* bk    = (const float*)d_in[6];
    const float* Wv    = (const float*)d_in[7];
    const float* bv    = (const float*)d_in[8];
    const float* ebias = (const float*)d_in[9];
    const float* Wo    = (const float*)d_in[10];
    const float* bo    = (const float*)d_in[11];
    const int* node_types = (const int*)d_in[12];
    const int* edge_index = (const int*)d_in[13];
    const int* edge_types = (const int*)d_in[14];

    float* out  = (float*)d_out;
    float* attn = (float*)d_out + (size_t)kN * kE;  // [H,N,N] output region

    float* ws = (float*)d_ws;
    float* Q = ws;                        // [N,E]
    float* K = ws + (size_t)kN * kE;      // [N,E]
    float* V = ws + 2 * (size_t)kN * kE;  // [N,E]
    int* counts = (int*)(ws + 3 * (size_t)kN * kE);      // [N]
    int* P      = counts + kN;                           // [N] starts -> ends after scatter
    unsigned short* entries = (unsigned short*)(P + kN); // [NE]
    float* OT = out;  // stage attn@V in the final-out region (out_proj is in-place safe)

    proj_kernel<<<kN, kE, 0, stream>>>(query, key_, value, Wq, bq, Wk, bk, Wv, bv,
                                       node_types, Q, K, V, counts);
    csr_count_kernel<<<kNE / 256, 256, 0, stream>>>(edge_index, counts);
    csr_scan_kernel<<<1, 1024, 0, stream>>>(counts, P);
    csr_scatter_kernel<<<kNE / 256, 256, 0, stream>>>(edge_index, edge_types, P, entries);
    attn_fused_kernel<<<dim3(kN / 4, kH), 512, 0, stream>>>(Q, K, V, P, entries, ebias,
                                                            attn, OT);
    out_proj_kernel<<<kN, kE, 0, stream>>>(OT, Wo, bo, out);
}